// Round 3
// baseline (779.548 us; speedup 1.0000x reference)
//
#include <hip/hip_runtime.h>

// ---------------------------------------------------------------------------
// SelfAttention: B=1024, C=N=256.  Per batch:
//   Q=(WqX+bq)/16 ; K=WkX+bk ; Vg=gamma*(WvX+bv) ; P=softmax_rows(Q K^T);
//   out = Vg P + x
// R3 pipeline: cvt weights (3 tiny) -> k_qkv2 (fused transpose-stage + 3
// T-form GEMMs, full batch) -> attn2 (full batch).
// ---------------------------------------------------------------------------

typedef __attribute__((ext_vector_type(8))) short bf16x8;
typedef __attribute__((ext_vector_type(4))) short bf16x4;
typedef __attribute__((ext_vector_type(4))) float f32x4;

#define MFMA16(a, b, c) __builtin_amdgcn_mfma_f32_16x16x32_bf16((a), (b), (c), 0, 0, 0)

static __device__ __forceinline__ unsigned short f2bf(float f) {
  unsigned int u = __float_as_uint(f);
  u += 0x7fffu + ((u >> 16) & 1u);  // round-to-nearest-even
  return (unsigned short)(u >> 16);
}

// 256 rows x 512B swizzled LDS buffer; XOR spreads stride-512B row accesses.
static __device__ __forceinline__ int swz(int row, int byteInRow) {
  return row * 512 + (byteInRow ^ ((row & 7) << 4));
}

// ---------------------------------------------------------------------------
// Kernel 0: f32 -> bf16 weight conversion (once per weight)
// ---------------------------------------------------------------------------
__global__ void k_cvt(const float* __restrict__ in, unsigned short* __restrict__ out) {
  const int i = blockIdx.x * 512 + threadIdx.x;
  out[i] = f2bf(in[i]);
}

// ---------------------------------------------------------------------------
// One T-form projection: dst[c][n] = (W X)[c][n]*sc + bsc[c], computed as
// C[n][c] = sum_i Xt[n][i] * W[c][i]  (A = Xt rows from LDS, B = W rows).
// C-layout: value = dst[c = ct*16+lo][n = r0 + rt*16 + hi*4 + reg] -> 8B stores.
// ---------------------------------------------------------------------------
static __device__ __forceinline__ void proj_t(
    const char* smem, const unsigned short* __restrict__ Wh,
    const float* __restrict__ bias, float sc, unsigned short* __restrict__ dst,
    int r0, int lo, int hi) {
  f32x4 acc[2][16];
#pragma unroll
  for (int i = 0; i < 2; ++i)
#pragma unroll
    for (int j = 0; j < 16; ++j) acc[i][j] = (f32x4){0.f, 0.f, 0.f, 0.f};
  for (int k0 = 0; k0 < 256; k0 += 32) {
    bf16x8 a0 = *(const bf16x8*)(smem + swz(r0 + lo, (k0 + hi * 8) * 2));
    bf16x8 a1 = *(const bf16x8*)(smem + swz(r0 + 16 + lo, (k0 + hi * 8) * 2));
#pragma unroll
    for (int ct = 0; ct < 16; ++ct) {
      bf16x8 bb = *(const bf16x8*)(Wh + (ct * 16 + lo) * 256 + k0 + hi * 8);
      acc[0][ct] = MFMA16(a0, bb, acc[0][ct]);
      acc[1][ct] = MFMA16(a1, bb, acc[1][ct]);
    }
  }
  float bsc[16];
#pragma unroll
  for (int ct = 0; ct < 16; ++ct) bsc[ct] = bias[ct * 16 + lo] * sc;
#pragma unroll
  for (int rt = 0; rt < 2; ++rt)
#pragma unroll
    for (int ct = 0; ct < 16; ++ct) {
      const int c = ct * 16 + lo;
      const int nb = r0 + rt * 16 + hi * 4;
      bf16x4 v;
#pragma unroll
      for (int reg = 0; reg < 4; ++reg)
        v[reg] = (short)f2bf(acc[rt][ct][reg] * sc + bsc[ct]);
      *(bf16x4*)(dst + c * 256 + nb) = v;
    }
}

// ---------------------------------------------------------------------------
// Kernel 1: per batch: stage Xt in LDS (tile-transpose), then Q/K/V T-GEMMs.
// LDS: [0,128K) M = Xt swizzled rows; [128K,144K) TS = 64x64 f32 tile.
// ---------------------------------------------------------------------------
__global__ __launch_bounds__(512, 2) void k_qkv2(
    const unsigned short* __restrict__ Wqh, const unsigned short* __restrict__ Wkh,
    const unsigned short* __restrict__ Wvh, const float* __restrict__ bq,
    const float* __restrict__ bk, const float* __restrict__ bv,
    const float* __restrict__ gamma, const float* __restrict__ x,
    unsigned short* __restrict__ Qo, unsigned short* __restrict__ Ko,
    unsigned short* __restrict__ Vo) {
  extern __shared__ char smem[];
  float* TS = (float*)(smem + 131072);
  const int b = blockIdx.x;
  const float* xb = x + (size_t)b * 65536;
  const int tid = threadIdx.x, w = tid >> 6, lane = tid & 63;
  const int lo = lane & 15, hi = lane >> 4;

  // ---- P0: stage Xt (bf16, swizzled [n][i]) via 16x (64x64) tile transpose ----
  const int lrow = tid >> 4;        // 0..31
  const int lcol = (tid & 15) * 4;  // 0..60
  for (int t = 0; t < 16; ++t) {
    const int c0 = (t >> 2) * 64, n0 = (t & 3) * 64;
#pragma unroll
    for (int rr = 0; rr < 2; ++rr) {
      const int r = lrow + rr * 32;
      *(float4*)&TS[r * 64 + lcol] = *(const float4*)(xb + (c0 + r) * 256 + n0 + lcol);
    }
    __syncthreads();
    {
      const int n = lane;  // 0..63 within tile
      bf16x8 v;
#pragma unroll
      for (int j = 0; j < 8; ++j) v[j] = (short)f2bf(TS[(w * 8 + j) * 64 + n]);
      const int row = n0 + n;
      const int byte = ((c0 + w * 8) * 2) ^ ((row & 7) << 4);
      *(bf16x8*)(smem + row * 512 + byte) = v;
    }
    __syncthreads();
  }

  // ---- P1-P3: three T-form projections (M is read-only; no barriers) ----
  const int r0 = w * 32;
  const size_t boff = (size_t)b * 65536;
  proj_t(smem, Wqh, bq, 0.0625f, Qo + boff, r0, lo, hi);
  proj_t(smem, Wkh, bk, 1.0f, Ko + boff, r0, lo, hi);
  proj_t(smem, Wvh, bv, gamma[0], Vo + boff, r0, lo, hi);
}

// ---------------------------------------------------------------------------
// Kernel 2: fused attention: P = softmax(Q K^T); out = V P + x
// ---------------------------------------------------------------------------
__global__ __launch_bounds__(512, 2) void attn2(
    const float* __restrict__ x, const unsigned short* __restrict__ Q,
    const unsigned short* __restrict__ K, const unsigned short* __restrict__ V,
    float* __restrict__ out) {
  extern __shared__ char smem[];
  const int b = blockIdx.x;
  const float* xb = x + (size_t)b * 65536;
  const unsigned short* Qb = Q + (size_t)b * 65536;
  const unsigned short* Kb = K + (size_t)b * 65536;
  const unsigned short* Vb = V + (size_t)b * 65536;
  const int tid = threadIdx.x, w = tid >> 6, lane = tid & 63, lo = lane & 15, hi = lane >> 4;

  // ---- Stage K into LDS (swizzled rows) ----
#pragma unroll
  for (int i = 0; i < 16; ++i) {
    const int o = i * 8192 + tid * 16;
    const int row = o >> 9, byte = o & 511;
    int4 t = *(const int4*)((const char*)Kb + o);
    *(int4*)(smem + row * 512 + (byte ^ ((row & 7) << 4))) = t;
  }
  __syncthreads();

  // ---- Phase A: S = Q K^T (wave owns 32 rows); softmax; P^T -> LDS ----
  {
    const int r0 = w * 32;
    f32x4 acc[2][16];
#pragma unroll
    for (int i = 0; i < 2; ++i)
#pragma unroll
      for (int j = 0; j < 16; ++j) acc[i][j] = (f32x4){0.f, 0.f, 0.f, 0.f};
    for (int k0 = 0; k0 < 256; k0 += 32) {
      bf16x8 a[2];
#pragma unroll
      for (int rt = 0; rt < 2; ++rt)
        a[rt] = *(const bf16x8*)(Qb + (r0 + rt * 16 + lo) * 256 + k0 + hi * 8);
#pragma unroll
      for (int ct = 0; ct < 16; ++ct) {
        bf16x8 bb = *(const bf16x8*)(smem + swz(ct * 16 + lo, (k0 + hi * 8) * 2));
#pragma unroll
        for (int rt = 0; rt < 2; ++rt) acc[rt][ct] = MFMA16(a[rt], bb, acc[rt][ct]);
      }
    }
#pragma unroll
    for (int rt = 0; rt < 2; ++rt)
#pragma unroll
      for (int reg = 0; reg < 4; ++reg) {
        float vals[16];
        float m = -3.0e38f;
#pragma unroll
        for (int ct = 0; ct < 16; ++ct) {
          const float v = acc[rt][ct][reg];
          vals[ct] = v;
          m = fmaxf(m, v);
        }
        m = fmaxf(m, __shfl_xor(m, 1));
        m = fmaxf(m, __shfl_xor(m, 2));
        m = fmaxf(m, __shfl_xor(m, 4));
        m = fmaxf(m, __shfl_xor(m, 8));
        float s = 0.f;
#pragma unroll
        for (int ct = 0; ct < 16; ++ct) {
          const float p = __expf(vals[ct] - m);
          vals[ct] = p;
          s += p;
        }
        s += __shfl_xor(s, 1);
        s += __shfl_xor(s, 2);
        s += __shfl_xor(s, 4);
        s += __shfl_xor(s, 8);
        const float inv = 1.0f / s;
#pragma unroll
        for (int ct = 0; ct < 16; ++ct) acc[rt][ct][reg] = vals[ct] * inv;
      }
    __syncthreads();  // all K reads done before overwrite
#pragma unroll
    for (int rt = 0; rt < 2; ++rt)
#pragma unroll
      for (int ct = 0; ct < 16; ++ct) {
        const int d = ct * 16 + lo;
        const int s0 = r0 + rt * 16 + hi * 4;
        bf16x4 v;
#pragma unroll
        for (int reg = 0; reg < 4; ++reg) v[reg] = (short)f2bf(acc[rt][ct][reg]);
        *(bf16x4*)(smem + swz(d, s0 * 2)) = v;
      }
  }
  __syncthreads();

  // ---- Phase B: O = V P ; out = O + x (gamma already in V) ----
  {
    const int r0 = (w >> 1) * 64, d0 = (w & 1) * 128;
    f32x4 acc[4][8];
#pragma unroll
    for (int i = 0; i < 4; ++i)
#pragma unroll
      for (int j = 0; j < 8; ++j) acc[i][j] = (f32x4){0.f, 0.f, 0.f, 0.f};
    for (int k0 = 0; k0 < 256; k0 += 32) {
      bf16x8 a[4];
#pragma unroll
      for (int rt = 0; rt < 4; ++rt)
        a[rt] = *(const bf16x8*)(Vb + (r0 + rt * 16 + lo) * 256 + k0 + hi * 8);
#pragma unroll
      for (int ct = 0; ct < 8; ++ct) {
        bf16x8 bb = *(const bf16x8*)(smem + swz(d0 + ct * 16 + lo, (k0 + hi * 8) * 2));
#pragma unroll
        for (int rt = 0; rt < 4; ++rt) acc[rt][ct] = MFMA16(a[rt], bb, acc[rt][ct]);
      }
    }
    float* ob = out + (size_t)b * 65536;
#pragma unroll
    for (int rt = 0; rt < 4; ++rt)
#pragma unroll
      for (int reg = 0; reg < 4; ++reg) {
        const int c = r0 + rt * 16 + hi * 4 + reg;
#pragma unroll
        for (int ct = 0; ct < 8; ++ct) {
          const int d = d0 + ct * 16 + lo;
          const int idx = c * 256 + d;
          ob[idx] = acc[rt][ct][reg] + xb[idx];
        }
      }
  }
}

// ---------------------------------------------------------------------------
extern "C" void kernel_launch(void* const* d_in, const int* in_sizes, int n_in,
                              void* d_out, int out_size, void* d_ws, size_t ws_size,
                              hipStream_t stream) {
  const float* x = (const float*)d_in[0];
  const float* Wq = (const float*)d_in[1];
  const float* bq = (const float*)d_in[2];
  const float* Wk = (const float*)d_in[3];
  const float* bk = (const float*)d_in[4];
  const float* Wv = (const float*)d_in[5];
  const float* bv = (const float*)d_in[6];
  const float* gamma = (const float*)d_in[7];
  float* out = (float*)d_out;

  const size_t EB = 65536;
  unsigned short* Qc = (unsigned short*)d_ws;           // 128 MiB
  unsigned short* Kc = Qc + (size_t)1024 * EB;          // 128 MiB
  unsigned short* Vc = Kc + (size_t)1024 * EB;          // 128 MiB
  unsigned short* Wqh = Vc + (size_t)1024 * EB;         // 128 KiB each
  unsigned short* Wkh = Wqh + EB;
  unsigned short* Wvh = Wkh + EB;
  const size_t need = ((size_t)3 * 1024 * EB + 3 * EB) * 2;
  if (ws_size < need) return;  // ~384.4 MiB

  hipLaunchKernelGGL(k_cvt, dim3(128), dim3(512), 0, stream, Wq, Wqh);
  hipLaunchKernelGGL(k_cvt, dim3(128), dim3(512), 0, stream, Wk, Wkh);
  hipLaunchKernelGGL(k_cvt, dim3(128), dim3(512), 0, stream, Wv, Wvh);

  hipLaunchKernelGGL(k_qkv2, dim3(1024), dim3(512), 147456, stream,
                     Wqh, Wkh, Wvh, bq, bk, bv, gamma, x, Qc, Kc, Vc);
  hipLaunchKernelGGL(attn2, dim3(1024), dim3(512), 131072, stream,
                     x, Qc, Kc, Vc, out);
}

// Round 4
// 518.689 us; speedup vs baseline: 1.5029x; 1.5029x over previous
//
#include <hip/hip_runtime.h>

// ---------------------------------------------------------------------------
// SelfAttention: B=1024, C=N=256.
//   Q=(WqX+bq)/16 ; K=WkX+bk ; Vg=gamma*(WvX+bv) ; P=softmax_rows(Q K^T);
//   out = Vg P + x
// R4 pipeline:
//   k_prep      : W3h[768][256] = bf16(scale_p * W_p), b3[768] (scales folded)
//   k_transpose : Xt[bn][i] = bf16(x[b][i][n])          (128 MiB)
//   k_gemm      : Y[768][262144] = W3h * Xt^T + b3      (flat GEMM, m97-style)
//   attn2       : per batch: P=softmax(Q K^T); out = V P + x   (strided on Y)
// ---------------------------------------------------------------------------

typedef __attribute__((ext_vector_type(8))) short bf16x8;
typedef __attribute__((ext_vector_type(4))) short bf16x4;
typedef __attribute__((ext_vector_type(4))) float f32x4;

#define MFMA16(a, b, c) __builtin_amdgcn_mfma_f32_16x16x32_bf16((a), (b), (c), 0, 0, 0)

#define GLDS16(g, l)                                                      \
  __builtin_amdgcn_global_load_lds(                                       \
      (const __attribute__((address_space(1))) void*)(g),                 \
      (__attribute__((address_space(3))) void*)(l), 16, 0, 0)

static __device__ __forceinline__ unsigned short f2bf(float f) {
  unsigned int u = __float_as_uint(f);
  u += 0x7fffu + ((u >> 16) & 1u);  // round-to-nearest-even
  return (unsigned short)(u >> 16);
}

// attn2's 256 rows x 512B swizzled LDS buffer.
static __device__ __forceinline__ int swz(int row, int byteInRow) {
  return row * 512 + (byteInRow ^ ((row & 7) << 4));
}

// ---------------------------------------------------------------------------
// Kernel 0: build stacked scaled weights + biases.
//   rows [0,256): Wq/16, bq/16 ; [256,512): Wk, bk ; [512,768): gamma*Wv, gamma*bv
// ---------------------------------------------------------------------------
__global__ void k_prep(const float* __restrict__ Wq, const float* __restrict__ bq,
                       const float* __restrict__ Wk, const float* __restrict__ bk,
                       const float* __restrict__ Wv, const float* __restrict__ bv,
                       const float* __restrict__ gamma,
                       unsigned short* __restrict__ W3h, float* __restrict__ b3) {
  const int r = blockIdx.x;  // 0..767
  const int p = r >> 8, sr = r & 255;
  const float s = (p == 0) ? 0.0625f : (p == 1 ? 1.0f : gamma[0]);
  const float* W = (p == 0) ? Wq : (p == 1 ? Wk : Wv);
  const float* bs = (p == 0) ? bq : (p == 1 ? bk : bv);
  W3h[r * 256 + threadIdx.x] = f2bf(W[sr * 256 + threadIdx.x] * s);
  if (threadIdx.x == 0) b3[r] = bs[sr] * s;
}

// ---------------------------------------------------------------------------
// Kernel 1: Xt[b*256 + n][i] = bf16(x[b][i][n])
// ---------------------------------------------------------------------------
__global__ void k_transpose(const float* __restrict__ x, unsigned short* __restrict__ xt) {
  __shared__ float tile[64][65];
  const int b = blockIdx.x;
  const float* xb = x + (size_t)b * 65536;
  unsigned short* xtb = xt + (size_t)b * 65536;
  const int t = threadIdx.x, tx = t & 63, ty = t >> 6;
  const int cp = t & 31, rb = t >> 5;
  for (int tb = 0; tb < 16; ++tb) {
    const int c0 = (tb >> 2) * 64, n0 = (tb & 3) * 64;
    __syncthreads();
#pragma unroll
    for (int yy = 0; yy < 16; ++yy) {
      const int r = ty + yy * 4;
      tile[r][tx] = xb[(c0 + r) * 256 + n0 + tx];
    }
    __syncthreads();
#pragma unroll
    for (int yy = 0; yy < 8; ++yy) {
      const int nl = rb + yy * 8;
      ushort2 v;
      v.x = f2bf(tile[2 * cp][nl]);
      v.y = f2bf(tile[2 * cp + 1][nl]);
      *(ushort2*)(xtb + (n0 + nl) * 256 + c0 + 2 * cp) = v;
    }
  }
}

// ---------------------------------------------------------------------------
// Kernel 2: flat GEMM  Y[m][bn] = sum_i W3h[m][i]*Xt[bn][i] + b3[m]
//   128x128 tile, BK=64, 256 threads (2x2 waves of 64x64), 32 KB LDS
//   single-buffer, global_load_lds(16B) with XOR-swizzled source/read.
// ---------------------------------------------------------------------------
__global__ __launch_bounds__(256, 4) void k_gemm(
    const unsigned short* __restrict__ W3h, const float* __restrict__ b3,
    const unsigned short* __restrict__ Xt, unsigned short* __restrict__ Y) {
  __shared__ char smem[32768];  // A tile [0,16K), B tile [16K,32K)
  // XCD-bijective swizzle (nwg=12288 % 8 == 0): co-locate the 6 r-tiles
  // sharing a B-tile on one XCD.
  const int bid = blockIdx.x;
  const int swzb = (bid & 7) * 1536 + (bid >> 3);
  const int r_t = swzb % 6, bn_t = swzb / 6;
  const int m0 = r_t * 128, n0 = bn_t * 128;
  const int tid = threadIdx.x, wv = tid >> 6, lane = tid & 63;
  const int lo = lane & 15, hi = lane >> 4;
  const int wm = wv >> 1, wn = wv & 1;

  f32x4 acc[4][4];
#pragma unroll
  for (int i = 0; i < 4; ++i)
#pragma unroll
    for (int j = 0; j < 4; ++j) acc[i][j] = (f32x4){0.f, 0.f, 0.f, 0.f};

  for (int k0 = 0; k0 < 256; k0 += 64) {
    // Stage A (W3h rows) and B (Xt rows): linear LDS dest, inverse-swizzled
    // global source (rule #21). Slot s=(row,g) holds global granule g^(row&7).
#pragma unroll
    for (int j = 0; j < 4; ++j) {
      const int s = j * 256 + tid;  // 0..1023
      const int row = s >> 3, gs = (s & 7) ^ (row & 7);
      GLDS16(W3h + (size_t)(m0 + row) * 256 + k0 + gs * 8,
             smem + j * 4096 + wv * 1024);
    }
#pragma unroll
    for (int j = 0; j < 4; ++j) {
      const int s = j * 256 + tid;
      const int row = s >> 3, gs = (s & 7) ^ (row & 7);
      GLDS16(Xt + (size_t)(n0 + row) * 256 + k0 + gs * 8,
             smem + 16384 + j * 4096 + wv * 1024);
    }
    __syncthreads();
#pragma unroll
    for (int kk = 0; kk < 2; ++kk) {
      bf16x8 a[4], b[4];
#pragma unroll
      for (int rt = 0; rt < 4; ++rt) {
        const int row = wm * 64 + rt * 16 + lo, g = kk * 4 + hi;
        a[rt] = *(const bf16x8*)(smem + row * 128 + ((g ^ (row & 7)) * 16));
      }
#pragma unroll
      for (int ct = 0; ct < 4; ++ct) {
        const int row = wn * 64 + ct * 16 + lo, g = kk * 4 + hi;
        b[ct] = *(const bf16x8*)(smem + 16384 + row * 128 + ((g ^ (row & 7)) * 16));
      }
#pragma unroll
      for (int rt = 0; rt < 4; ++rt)
#pragma unroll
        for (int ct = 0; ct < 4; ++ct) acc[rt][ct] = MFMA16(a[rt], b[ct], acc[rt][ct]);
    }
    __syncthreads();
  }

  // Epilogue: bias, bf16, swizzled-LDS repack, coalesced 16B stores.
  float b3v[4][4];
#pragma unroll
  for (int rt = 0; rt < 4; ++rt)
#pragma unroll
    for (int reg = 0; reg < 4; ++reg)
      b3v[rt][reg] = b3[m0 + wm * 64 + rt * 16 + hi * 4 + reg];
#pragma unroll
  for (int rt = 0; rt < 4; ++rt)
#pragma unroll
    for (int ct = 0; ct < 4; ++ct)
#pragma unroll
      for (int reg = 0; reg < 4; ++reg) {
        const int m = wm * 64 + rt * 16 + hi * 4 + reg;
        const int n = wn * 64 + ct * 16 + lo;
        *(unsigned short*)(smem + m * 256 + ((n * 2) ^ ((m & 7) << 4))) =
            f2bf(acc[rt][ct][reg] + b3v[rt][reg]);
      }
  __syncthreads();
#pragma unroll
  for (int j = 0; j < 8; ++j) {
    const int s = j * 256 + tid;        // 0..2047 16B-chunks
    const int m = s >> 4, p = s & 15;
    const int ng = p ^ (m & 7);         // logical n-granule
    int4 v = *(const int4*)(smem + m * 256 + p * 16);
    *(int4*)((char*)Y + ((size_t)(m0 + m) * 262144 + n0 + ng * 8) * 2) = v;
  }
}

// ---------------------------------------------------------------------------
// Kernel 3: fused attention (strided on Y): P = softmax(Q K^T); out = V P + x
// ---------------------------------------------------------------------------
__global__ __launch_bounds__(512, 2) void attn2(
    const float* __restrict__ x, const unsigned short* __restrict__ Y,
    float* __restrict__ out) {
  extern __shared__ char smem[];
  const size_t S = 262144;  // Y row stride (elements)
  const int b = blockIdx.x;
  const float* xb = x + (size_t)b * 65536;
  const unsigned short* Qb = Y + (size_t)b * 256;
  const unsigned short* Kb = Qb + 256 * S;
  const unsigned short* Vb = Qb + 512 * S;
  const int tid = threadIdx.x, w = tid >> 6, lane = tid & 63, lo = lane & 15, hi = lane >> 4;

  // ---- Stage K into LDS (swizzled rows) ----
#pragma unroll
  for (int i = 0; i < 16; ++i) {
    const int idx = i * 512 + tid;  // 0..8191 16B-chunks
    const int row = idx >> 5, c16 = idx & 31;
    int4 t = *(const int4*)(Kb + (size_t)row * S + c16 * 8);
    *(int4*)(smem + row * 512 + ((c16 * 16) ^ ((row & 7) << 4))) = t;
  }
  __syncthreads();

  // ---- Phase A: S = Q K^T (wave owns 32 rows); softmax; P^T -> LDS ----
  {
    const int r0 = w * 32;
    f32x4 acc[2][16];
#pragma unroll
    for (int i = 0; i < 2; ++i)
#pragma unroll
      for (int j = 0; j < 16; ++j) acc[i][j] = (f32x4){0.f, 0.f, 0.f, 0.f};
    for (int k0 = 0; k0 < 256; k0 += 32) {
      bf16x8 a[2];
#pragma unroll
      for (int rt = 0; rt < 2; ++rt)
        a[rt] = *(const bf16x8*)(Qb + (size_t)(r0 + rt * 16 + lo) * S + k0 + hi * 8);
#pragma unroll
      for (int ct = 0; ct < 16; ++ct) {
        bf16x8 bb = *(const bf16x8*)(smem + swz(ct * 16 + lo, (k0 + hi * 8) * 2));
#pragma unroll
        for (int rt = 0; rt < 2; ++rt) acc[rt][ct] = MFMA16(a[rt], bb, acc[rt][ct]);
      }
    }
#pragma unroll
    for (int rt = 0; rt < 2; ++rt)
#pragma unroll
      for (int reg = 0; reg < 4; ++reg) {
        float vals[16];
        float m = -3.0e38f;
#pragma unroll
        for (int ct = 0; ct < 16; ++ct) {
          const float v = acc[rt][ct][reg];
          vals[ct] = v;
          m = fmaxf(m, v);
        }
        m = fmaxf(m, __shfl_xor(m, 1));
        m = fmaxf(m, __shfl_xor(m, 2));
        m = fmaxf(m, __shfl_xor(m, 4));
        m = fmaxf(m, __shfl_xor(m, 8));
        float s = 0.f;
#pragma unroll
        for (int ct = 0; ct < 16; ++ct) {
          const float p = __expf(vals[ct] - m);
          vals[ct] = p;
          s += p;
        }
        s += __shfl_xor(s, 1);
        s += __shfl_xor(s, 2);
        s += __shfl_xor(s, 4);
        s += __shfl_xor(s, 8);
        const float inv = 1.0f / s;
#pragma unroll
        for (int ct = 0; ct < 16; ++ct) acc[rt][ct][reg] = vals[ct] * inv;
      }
    __syncthreads();  // all K reads done before overwrite
#pragma unroll
    for (int rt = 0; rt < 2; ++rt)
#pragma unroll
      for (int ct = 0; ct < 16; ++ct) {
        const int d = ct * 16 + lo;
        const int s0 = r0 + rt * 16 + hi * 4;
        bf16x4 v;
#pragma unroll
        for (int reg = 0; reg < 4; ++reg) v[reg] = (short)f2bf(acc[rt][ct][reg]);
        *(bf16x4*)(smem + swz(d, s0 * 2)) = v;
      }
  }
  __syncthreads();

  // ---- Phase B: O = V P ; out = O + x (gamma already in V) ----
  {
    const int r0 = (w >> 1) * 64, d0 = (w & 1) * 128;
    f32x4 acc[4][8];
#pragma unroll
    for (int i = 0; i < 4; ++i)
#pragma unroll
      for (int j = 0; j < 8; ++j) acc[i][j] = (f32x4){0.f, 0.f, 0.f, 0.f};
    for (int k0 = 0; k0 < 256; k0 += 32) {
      bf16x8 a[4];
#pragma unroll
      for (int rt = 0; rt < 4; ++rt)
        a[rt] = *(const bf16x8*)(Vb + (size_t)(r0 + rt * 16 + lo) * S + k0 + hi * 8);
#pragma unroll
      for (int ct = 0; ct < 8; ++ct) {
        bf16x8 bb = *(const bf16x8*)(smem + swz(d0 + ct * 16 + lo, (k0 + hi * 8) * 2));
#pragma unroll
        for (int rt = 0; rt < 4; ++rt) acc[rt][ct] = MFMA16(a[rt], bb, acc[rt][ct]);
      }
    }
    float* ob = out + (size_t)b * 65536;
#pragma unroll
    for (int rt = 0; rt < 4; ++rt)
#pragma unroll
      for (int reg = 0; reg < 4; ++reg) {
        const int c = r0 + rt * 16 + hi * 4 + reg;
#pragma unroll
        for (int ct = 0; ct < 8; ++ct) {
          const int d = d0 + ct * 16 + lo;
          const int idx = c * 256 + d;
          ob[idx] = acc[rt][ct][reg] + xb[idx];
        }
      }
  }
}

// ---------------------------------------------------------------------------
extern "C" void kernel_launch(void* const* d_in, const int* in_sizes, int n_in,
                              void* d_out, int out_size, void* d_ws, size_t ws_size,
                              hipStream_t stream) {
  const float* x = (const float*)d_in[0];
  const float* Wq = (const float*)d_in[1];
  const float* bq = (const float*)d_in[2];
  const float* Wk = (const float*)d_in[3];
  const float* bk = (const float*)d_in[4];
  const float* Wv = (const float*)d_in[5];
  const float* bv = (const float*)d_in[6];
  const float* gamma = (const float*)d_in[7];
  float* out = (float*)d_out;

  unsigned short* Y = (unsigned short*)d_ws;                 // 768*262144 bf16 = 384 MiB
  unsigned short* Xt = Y + (size_t)768 * 262144;             // 1024*65536 bf16 = 128 MiB
  unsigned short* W3h = Xt + (size_t)1024 * 65536;           // 384 KiB
  float* b3 = (float*)(W3h + 768 * 256);                     // 3 KiB
  const size_t need = ((size_t)768 * 262144 + (size_t)1024 * 65536 + 768 * 256) * 2 + 768 * 4;
  if (ws_size < need) return;  // ~512.4 MiB

  hipLaunchKernelGGL(k_prep, dim3(768), dim3(256), 0, stream,
                     Wq, bq, Wk, bk, Wv, bv, gamma, W3h, b3);
  hipLaunchKernelGGL(k_transpose, dim3(1024), dim3(256), 0, stream, x, Xt);
  hipLaunchKernelGGL(k_gemm, dim3(12288), dim3(256), 0, stream, W3h, b3, Xt, Y);
  hipLaunchKernelGGL(attn2, dim3(1024), dim3(512), 131072, stream, x, Y, out);
}